// Round 6
// baseline (327.988 us; speedup 1.0000x reference)
//
#include <hip/hip_runtime.h>
#include <hip/hip_bf16.h>

#define B_ 8
#define T_ 4096
#define D_ 1024
#define H_ 1024

typedef __attribute__((ext_vector_type(8))) short short8;
typedef __attribute__((ext_vector_type(4))) float floatx4;

#define GLOAD16(gptr, lptr) \
  __builtin_amdgcn_global_load_lds((const __attribute__((address_space(1))) void*)(gptr), \
                                   (__attribute__((address_space(3))) void*)(lptr), 16, 0, 0)

__device__ __forceinline__ ushort f2b(float f) {
  unsigned x = __builtin_bit_cast(unsigned, f);
  unsigned r = (x + 0x7fffu + ((x >> 16) & 1u)) >> 16;  // RNE, inputs finite
  return (ushort)r;
}
__device__ __forceinline__ float b2f(ushort u) {
  return __builtin_bit_cast(float, (unsigned)u << 16);
}

__global__ void cvt_kernel(const float* __restrict__ in, ushort* __restrict__ out, int n) {
  int idx = blockIdx.x * blockDim.x + threadIdx.x;
  int stride = gridDim.x * blockDim.x;
  for (long i = (long)idx * 8; i < n; i += (long)stride * 8) {
    const float4 f0 = *(const float4*)(in + i);
    const float4 f1 = *(const float4*)(in + i + 4);
    union { ushort u[8]; uint4 v; } r;
    r.u[0] = f2b(f0.x); r.u[1] = f2b(f0.y); r.u[2] = f2b(f0.z); r.u[3] = f2b(f0.w);
    r.u[4] = f2b(f1.x); r.u[5] = f2b(f1.y); r.u[6] = f2b(f1.z); r.u[7] = f2b(f1.w);
    *(uint4*)(out + i) = r.v;
  }
}

// converts the 3 weight matrices in one launch; blockIdx.y picks the pair
__global__ void cvt3_kernel(const float* __restrict__ w0, const float* __restrict__ w1,
                            const float* __restrict__ w2, ushort* __restrict__ out, int n) {
  const float* in = (blockIdx.y == 0) ? w0 : (blockIdx.y == 1) ? w1 : w2;
  ushort* o = out + (size_t)blockIdx.y * n;
  int idx = blockIdx.x * blockDim.x + threadIdx.x;
  int stride = gridDim.x * blockDim.x;
  for (long i = (long)idx * 8; i < n; i += (long)stride * 8) {
    const float4 f0 = *(const float4*)(in + i);
    const float4 f1 = *(const float4*)(in + i + 4);
    union { ushort u[8]; uint4 v; } r;
    r.u[0] = f2b(f0.x); r.u[1] = f2b(f0.y); r.u[2] = f2b(f0.z); r.u[3] = f2b(f0.w);
    r.u[4] = f2b(f1.x); r.u[5] = f2b(f1.y); r.u[6] = f2b(f1.z); r.u[7] = f2b(f1.w);
    *(uint4*)(o + i) = r.v;
  }
}

// ----------------------------------------------------------------------------
// 256x256 B^T GEMM, m201 geometry: 8 waves (2 wr x 4 wc), wave tile 128x64,
// acc[8][4] floatx4. BK=32, FOUR LDS buffers (A 4x16KB + B 4x16KB = 128 KiB).
// Per K-tile t: 2 windows of 16 MFMA (m-halves). Window 1 reads A(mh0)+B and
// stages A(t+3); window 2 reads A(mh1), stages B(t+3), then vmcnt(8) ensures
// tile t+1 landed. Stage regions (buf (t-1)&3) are read-free since the prior
// tile's windows -> barrier discipline makes the overwrite safe.
// LDS swizzle: rows grouped in pairs (128B groups of 8 x 16B chunks),
// phys chunk = logical ^ (rowpair&7); reads are 2 lanes/bank (free, per R3).
// Source is pre-swizzled per-thread; LDS dest stays linear for gload_lds.
// ----------------------------------------------------------------------------
template <int NCOLS, bool QEPI>
__global__ __launch_bounds__(512, 2) void gemm_bt(
    const ushort* __restrict__ Am, const ushort* __restrict__ Bm,
    ushort* __restrict__ KVout, const float* __restrict__ bq,
    const float* __restrict__ weighted, float* __restrict__ out) {
  extern __shared__ ushort lds[];
  ushort* const Abuf = lds;           // 4 x 8192 elems
  ushort* const Bbuf = lds + 32768;   // 4 x 8192 elems

  const int tid = threadIdx.x;
  const int lane = tid & 63;
  const int w = tid >> 6;     // 0..7
  const int wr = w >> 2;      // 0..1  (128-row granule)
  const int wc = w & 3;       // 0..3  (64-col granule)
  const int R0 = blockIdx.x * 256;
  const int C0 = blockIdx.y * 256;

  // ---- staging addressing (pre-swizzled source, linear LDS dest) ----
  // chunk idx = g*512 + tid; rp = idx>>3, phys = idx&7,
  // logical = phys ^ (rp&7); row = rp*2 + (logical>>2), kchunk = logical&3.
  const int lc = (tid & 7) ^ ((tid >> 3) & 7);
  const int r0 = ((tid >> 3) << 1) + (lc >> 2);
  const int kc0 = (lc & 3) * 8;
  const ushort* asrc = Am + (size_t)(R0 + r0) * D_ + kc0;
  const ushort* bsrc = Bm + (size_t)(C0 + r0) * D_ + kc0;

  auto stageA = [&](int t) {
    const int nb = t & 3;
    GLOAD16(asrc + t * 32, Abuf + nb * 8192 + tid * 8);
    GLOAD16(asrc + t * 32 + (size_t)128 * D_, Abuf + nb * 8192 + (512 + tid) * 8);
  };
  auto stageB = [&](int t) {
    const int nb = t & 3;
    GLOAD16(bsrc + t * 32, Bbuf + nb * 8192 + tid * 8);
    GLOAD16(bsrc + t * 32 + (size_t)128 * D_, Bbuf + nb * 8192 + (512 + tid) * 8);
  };

  // ---- fragment read addressing ----
  // row = base + m*16 (A) / n*16 (B); c = lane>>4 (k-chunk of 32);
  // slot = (4*(row&1) + c) ^ ((row>>1)&7)  [const per lane];
  // elem addr = (base>>1)*64 + slot*8 + m*512 (+ buf*8192).
  const int c = lane >> 4;
  const int baseA = wr * 128 + (lane & 15);
  const int baseB = wc * 64 + (lane & 15);
  const int SA = (4 * (lane & 1) + c) ^ ((baseA >> 1) & 7);
  const int SB = (4 * (lane & 1) + c) ^ ((baseB >> 1) & 7);
  const ushort* aRd = lds + (baseA >> 1) * 64 + SA * 8;
  const ushort* bRd = lds + 32768 + (baseB >> 1) * 64 + SB * 8;

  floatx4 acc[8][4] = {};

  stageA(0); stageB(0);
  stageA(1); stageB(1);
  stageA(2); stageB(2);
  asm volatile("s_waitcnt vmcnt(8)" ::: "memory");  // tile 0 landed
  __builtin_amdgcn_s_barrier();

  const int NT = D_ / 32;  // 32
  for (int t = 0; t < NT; ++t) {
    const int boff = (t & 3) * 8192;
    short8 a[4], b[4];

    // ---- window 1: m-half 0 ----
#pragma unroll
    for (int m = 0; m < 4; ++m) a[m] = *(const short8*)(aRd + boff + m * 512);
#pragma unroll
    for (int n = 0; n < 4; ++n) b[n] = *(const short8*)(bRd + boff + n * 512);
    if (t < NT - 3) stageA(t + 3);
    __builtin_amdgcn_s_barrier();
    asm volatile("s_waitcnt lgkmcnt(0)" ::: "memory");
    __builtin_amdgcn_sched_barrier(0);
    __builtin_amdgcn_s_setprio(1);
#pragma unroll
    for (int m = 0; m < 4; ++m)
#pragma unroll
      for (int n = 0; n < 4; ++n)
        acc[m][n] = __builtin_amdgcn_mfma_f32_16x16x32_bf16(a[m], b[n], acc[m][n], 0, 0, 0);
    __builtin_amdgcn_s_setprio(0);
    __builtin_amdgcn_s_barrier();

    // ---- window 2: m-half 1 (B frags reused from registers) ----
#pragma unroll
    for (int m = 0; m < 4; ++m) a[m] = *(const short8*)(aRd + boff + (m + 4) * 512);
    if (t < NT - 3) stageB(t + 3);
    __builtin_amdgcn_s_barrier();
    asm volatile("s_waitcnt lgkmcnt(0)" ::: "memory");
    __builtin_amdgcn_sched_barrier(0);
    __builtin_amdgcn_s_setprio(1);
#pragma unroll
    for (int m = 0; m < 4; ++m)
#pragma unroll
      for (int n = 0; n < 4; ++n)
        acc[m + 4][n] = __builtin_amdgcn_mfma_f32_16x16x32_bf16(a[m], b[n], acc[m + 4][n], 0, 0, 0);
    __builtin_amdgcn_s_setprio(0);

    if (t < NT - 3)       { asm volatile("s_waitcnt vmcnt(8)" ::: "memory"); }
    else if (t == NT - 3) { asm volatile("s_waitcnt vmcnt(4)" ::: "memory"); }
    else                  { asm volatile("s_waitcnt vmcnt(0)" ::: "memory"); }
    __builtin_amdgcn_s_barrier();
  }

  // ---- epilogue ----
  const int orow = R0 + wr * 128 + (lane >> 4) * 4;  // + m*16 + r
  const int ocol = C0 + wc * 64 + (lane & 15);       // + n*16
  if constexpr (QEPI) {
    float bqc[4];
#pragma unroll
    for (int n = 0; n < 4; ++n) bqc[n] = bq[ocol + n * 16];
#pragma unroll
    for (int m = 0; m < 8; ++m)
#pragma unroll
      for (int n = 0; n < 4; ++n)
#pragma unroll
        for (int r = 0; r < 4; ++r) {
          int row = orow + m * 16 + r;
          int col = ocol + n * 16;
          float q = acc[m][n][r] + bqc[n];
          float sig = 1.f / (1.f + __expf(-q));
          out[(size_t)row * NCOLS + col] =
              sig * weighted[(size_t)(row & (T_ - 1)) * H_ + col];
        }
  } else {
#pragma unroll
    for (int m = 0; m < 8; ++m)
#pragma unroll
      for (int n = 0; n < 4; ++n)
#pragma unroll
        for (int r = 0; r < 4; ++r)
          KVout[(size_t)(orow + m * 16 + r) * NCOLS + ocol + n * 16] = f2b(acc[m][n][r]);
  }
}

// Batch reduction: weighted[t,h] = sum_b exp(K+bk+wb)*(V+bv) / sum_b exp(K+bk+wb)
__global__ __launch_bounds__(256) void reduce_kernel(
    const ushort* __restrict__ KV, const float* __restrict__ bk,
    const float* __restrict__ bv, const float* __restrict__ wb,
    float* __restrict__ weighted) {
  const int gid = blockIdx.x * 256 + threadIdx.x;  // 0 .. T*H/8
  const int t = gid >> 7;
  const int h0 = (gid & 127) * 8;

  float bk8[8], bv8[8], wb8[8];
#pragma unroll
  for (int j = 0; j < 8; ++j) {
    bk8[j] = bk[h0 + j];
    bv8[j] = bv[h0 + j];
    wb8[j] = wb[h0 + j];
  }

  float sn[8] = {}, sw[8] = {};
  for (int b = 0; b < B_; ++b) {
    const size_t rowoff = (size_t)(b * T_ + t) * (2 * H_);
    const short8 k8 = *(const short8*)(KV + rowoff + h0);
    const short8 v8 = *(const short8*)(KV + rowoff + H_ + h0);
#pragma unroll
    for (int j = 0; j < 8; ++j) {
      float e = __expf(b2f((ushort)k8[j]) + bk8[j] + wb8[j]);
      sn[j] += e;
      sw[j] += e * (b2f((ushort)v8[j]) + bv8[j]);
    }
  }
  float4 o0, o1;
  o0.x = sw[0] / sn[0]; o0.y = sw[1] / sn[1]; o0.z = sw[2] / sn[2]; o0.w = sw[3] / sn[3];
  o1.x = sw[4] / sn[4]; o1.y = sw[5] / sn[5]; o1.z = sw[6] / sn[6]; o1.w = sw[7] / sn[7];
  *(float4*)(weighted + (size_t)t * H_ + h0) = o0;
  *(float4*)(weighted + (size_t)t * H_ + h0 + 4) = o1;
}

extern "C" void kernel_launch(void* const* d_in, const int* in_sizes, int n_in,
                              void* d_out, int out_size, void* d_ws, size_t ws_size,
                              hipStream_t stream) {
  (void)in_sizes; (void)n_in; (void)out_size; (void)ws_size;
  const float* x = (const float*)d_in[0];
  const float* Wq = (const float*)d_in[1];
  const float* bq = (const float*)d_in[2];
  const float* Wk = (const float*)d_in[3];
  const float* bk = (const float*)d_in[4];
  const float* Wv = (const float*)d_in[5];
  const float* bv = (const float*)d_in[6];
  const float* wbias = (const float*)d_in[7];
  float* out = (float*)d_out;

  char* ws = (char*)d_ws;
  const size_t XN = (size_t)B_ * T_ * D_;   // 33,554,432
  const size_t WN = (size_t)H_ * D_;        // 1,048,576
  ushort* xb   = (ushort*)ws;                            // 64 MiB
  ushort* Wqb  = (ushort*)(ws + XN * 2);                 // 2 MiB
  ushort* Wkvb = Wqb + WN;                               // 4 MiB (Wk|Wv contiguous)
  float* weighted = (float*)(ws + XN * 2 + 3 * WN * 2);  // 16 MiB
  ushort* KV = (ushort*)(ws + XN * 2 + 3 * WN * 2 + (size_t)T_ * H_ * 4);  // 128 MiB

  (void)hipFuncSetAttribute((const void*)gemm_bt<2048, false>,
                            hipFuncAttributeMaxDynamicSharedMemorySize, 131072);
  (void)hipFuncSetAttribute((const void*)gemm_bt<1024, true>,
                            hipFuncAttributeMaxDynamicSharedMemorySize, 131072);

  cvt_kernel<<<2048, 256, 0, stream>>>(x, xb, (int)XN);
  cvt3_kernel<<<dim3(512, 3), 256, 0, stream>>>(Wq, Wk, Wv, Wqb, (int)WN);

  gemm_bt<2048, false><<<dim3((B_ * T_) / 256, 2048 / 256), 512, 131072, stream>>>(
      xb, Wkvb, KV, nullptr, nullptr, nullptr);
  reduce_kernel<<<(T_ * H_ / 8) / 256, 256, 0, stream>>>(KV, bk, bv, wbias, weighted);
  gemm_bt<1024, true><<<dim3((B_ * T_) / 256, 1024 / 256), 512, 131072, stream>>>(
      xb, Wqb, nullptr, bq, weighted, out);
}

// Round 7
// 314.376 us; speedup vs baseline: 1.0433x; 1.0433x over previous
//
#include <hip/hip_runtime.h>
#include <hip/hip_bf16.h>

#define B_ 8
#define T_ 4096
#define D_ 1024
#define H_ 1024

typedef __attribute__((ext_vector_type(8))) short short8;
typedef __attribute__((ext_vector_type(4))) float floatx4;

#define GLOAD16(gptr, lptr) \
  __builtin_amdgcn_global_load_lds((const __attribute__((address_space(1))) void*)(gptr), \
                                   (__attribute__((address_space(3))) void*)(lptr), 16, 0, 0)

__device__ __forceinline__ ushort f2b(float f) {
  unsigned x = __builtin_bit_cast(unsigned, f);
  unsigned r = (x + 0x7fffu + ((x >> 16) & 1u)) >> 16;  // RNE, inputs finite
  return (ushort)r;
}
__device__ __forceinline__ float b2f(ushort u) {
  return __builtin_bit_cast(float, (unsigned)u << 16);
}

__global__ void cvt_kernel(const float* __restrict__ in, ushort* __restrict__ out, int n) {
  int idx = blockIdx.x * blockDim.x + threadIdx.x;
  int stride = gridDim.x * blockDim.x;
  for (long i = (long)idx * 8; i < n; i += (long)stride * 8) {
    const float4 f0 = *(const float4*)(in + i);
    const float4 f1 = *(const float4*)(in + i + 4);
    union { ushort u[8]; uint4 v; } r;
    r.u[0] = f2b(f0.x); r.u[1] = f2b(f0.y); r.u[2] = f2b(f0.z); r.u[3] = f2b(f0.w);
    r.u[4] = f2b(f1.x); r.u[5] = f2b(f1.y); r.u[6] = f2b(f1.z); r.u[7] = f2b(f1.w);
    *(uint4*)(out + i) = r.v;
  }
}

__global__ void cvt3_kernel(const float* __restrict__ w0, const float* __restrict__ w1,
                            const float* __restrict__ w2, ushort* __restrict__ out, int n) {
  const float* in = (blockIdx.y == 0) ? w0 : (blockIdx.y == 1) ? w1 : w2;
  ushort* o = out + (size_t)blockIdx.y * n;
  int idx = blockIdx.x * blockDim.x + threadIdx.x;
  int stride = gridDim.x * blockDim.x;
  for (long i = (long)idx * 8; i < n; i += (long)stride * 8) {
    const float4 f0 = *(const float4*)(in + i);
    const float4 f1 = *(const float4*)(in + i + 4);
    union { ushort u[8]; uint4 v; } r;
    r.u[0] = f2b(f0.x); r.u[1] = f2b(f0.y); r.u[2] = f2b(f0.z); r.u[3] = f2b(f0.w);
    r.u[4] = f2b(f1.x); r.u[5] = f2b(f1.y); r.u[6] = f2b(f1.z); r.u[7] = f2b(f1.w);
    *(uint4*)(o + i) = r.v;
  }
}

// ----------------------------------------------------------------------------
// 256x256 B^T GEMM, quadrant-phase schedule (m201-faithful).
// 8 waves (2wr x 4wc), wave tile 128x64, acc[8][4]. BK=64, 2 dbuf (128 KiB).
// Per K-tile, 4 phases over acc quadrants; phase reads: 8/4/8/0 b128 (operand
// register reuse across phases); stage: Bh0(t+2)@P2, {Bh1,Ah0,Ah1}(t+2)@P3
// (safe: all reads of the overwritten half completed before the preceding
// barrier via per-phase lgkmcnt(0)); single vmcnt(8) at P3 -> tile t+1 landed,
// never drains to 0 in steady state.
// Swizzle both-sides: 16B chunk' = chunk ^ (row&7); 2-way reads (free).
// Epilogue: in-LDS transpose (2 halves) -> coalesced uint4/float4 stores.
// ----------------------------------------------------------------------------
template <int NCOLS, bool QEPI>
__global__ __launch_bounds__(512, 2) void gemm_bt(
    const ushort* __restrict__ Am, const ushort* __restrict__ Bm,
    ushort* __restrict__ KVout, const float* __restrict__ bq,
    const float* __restrict__ weighted, float* __restrict__ out) {
  extern __shared__ ushort lds[];

  const int tid = threadIdx.x;
  const int lane = tid & 63;
  const int w = tid >> 6;     // 0..7
  const int wr = w >> 2;      // 0..1  (128-row granule)
  const int wc = w & 3;       // 0..3  (64-col granule)
  const int R0 = blockIdx.x * 256;
  const int C0 = blockIdx.y * 256;

  // staging: chunk ci = j*512+tid of a 128x64 half-tile; row=ci>>3, phys=ci&7,
  // source logical chunk = phys ^ (row&7) (j*64 = 0 mod 8 -> const per thread)
  const int r0 = tid >> 3;                       // 0..63
  const int lc = (tid & 7) ^ ((tid >> 3) & 7);
  const ushort* asrc = Am + (size_t)(R0 + r0) * D_ + lc * 8;
  const ushort* bsrc = Bm + (size_t)(C0 + r0) * D_ + lc * 8;

  auto stageA = [&](int t, int h) {
    ushort* dst = lds + (t & 1) * 16384 + h * 8192 + tid * 8;
    const ushort* s = asrc + t * 64 + (size_t)(h * 128) * D_;
    GLOAD16(s, dst);
    GLOAD16(s + (size_t)64 * D_, dst + 4096);
  };
  auto stageB = [&](int t, int h) {
    ushort* dst = lds + 32768 + (t & 1) * 16384 + h * 8192 + tid * 8;
    const ushort* s = bsrc + t * 64 + (size_t)(h * 128) * D_;
    GLOAD16(s, dst);
    GLOAD16(s + (size_t)64 * D_, dst + 4096);
  };

  // fragment read offsets (element units); row*64 + physchunk*8
  const int rowA = wr * 128 + (lane & 15);
  const int rowB = wc * 64 + (lane & 15);
  int aOff[2], bOff[2];
#pragma unroll
  for (int k = 0; k < 2; ++k) {
    aOff[k] = rowA * 64 + (((k * 4) + (lane >> 4)) ^ (lane & 7)) * 8;
    bOff[k] = rowB * 64 + (((k * 4) + (lane >> 4)) ^ (lane & 7)) * 8;
  }

  floatx4 acc[8][4] = {};
  short8 aF[4][2], bA[2][2], bB[2][2];

  stageB(0, 0); stageB(0, 1); stageA(0, 0); stageA(0, 1);
  stageB(1, 0); stageB(1, 1); stageA(1, 0); stageA(1, 1);
  asm volatile("s_waitcnt vmcnt(8)" ::: "memory");  // tile 0 landed
  __builtin_amdgcn_s_barrier();

  const int NT = D_ / 64;  // 16
  for (int t = 0; t < NT; ++t) {
    const ushort* Ab = lds + (t & 1) * 16384;
    const ushort* Bb = lds + 32768 + (t & 1) * 16384;

    // ---- P0: read A m0-3 (8) + B n0-1 (4); mfma q(m0-3, n0-1) ----
#pragma unroll
    for (int m = 0; m < 4; ++m)
#pragma unroll
      for (int k = 0; k < 2; ++k)
        aF[m][k] = *(const short8*)(Ab + m * 1024 + aOff[k]);
#pragma unroll
    for (int n = 0; n < 2; ++n)
#pragma unroll
      for (int k = 0; k < 2; ++k)
        bA[n][k] = *(const short8*)(Bb + n * 1024 + bOff[k]);
    __builtin_amdgcn_s_barrier();
    asm volatile("s_waitcnt lgkmcnt(0)" ::: "memory");
    __builtin_amdgcn_sched_barrier(0);
    __builtin_amdgcn_s_setprio(1);
#pragma unroll
    for (int m = 0; m < 4; ++m)
#pragma unroll
      for (int n = 0; n < 2; ++n)
#pragma unroll
        for (int k = 0; k < 2; ++k)
          acc[m][n] = __builtin_amdgcn_mfma_f32_16x16x32_bf16(aF[m][k], bA[n][k], acc[m][n], 0, 0, 0);
    __builtin_amdgcn_s_setprio(0);
    __builtin_amdgcn_s_barrier();

    // ---- P1: read B n2-3 (4); mfma q(m0-3, n2-3) ----
#pragma unroll
    for (int n = 0; n < 2; ++n)
#pragma unroll
      for (int k = 0; k < 2; ++k)
        bB[n][k] = *(const short8*)(Bb + (n + 2) * 1024 + bOff[k]);
    __builtin_amdgcn_s_barrier();
    asm volatile("s_waitcnt lgkmcnt(0)" ::: "memory");
    __builtin_amdgcn_sched_barrier(0);
    __builtin_amdgcn_s_setprio(1);
#pragma unroll
    for (int m = 0; m < 4; ++m)
#pragma unroll
      for (int n = 0; n < 2; ++n)
#pragma unroll
        for (int k = 0; k < 2; ++k)
          acc[m][n + 2] = __builtin_amdgcn_mfma_f32_16x16x32_bf16(aF[m][k], bB[n][k], acc[m][n + 2], 0, 0, 0);
    __builtin_amdgcn_s_setprio(0);
    __builtin_amdgcn_s_barrier();

    // ---- P2: read A m4-7 (8); stage Bh0(t+2); mfma q(m4-7, n0-1) ----
#pragma unroll
    for (int m = 0; m < 4; ++m)
#pragma unroll
      for (int k = 0; k < 2; ++k)
        aF[m][k] = *(const short8*)(Ab + (m + 4) * 1024 + aOff[k]);
    if (t + 2 < NT) stageB(t + 2, 0);
    __builtin_amdgcn_s_barrier();
    asm volatile("s_waitcnt lgkmcnt(0)" ::: "memory");
    __builtin_amdgcn_sched_barrier(0);
    __builtin_amdgcn_s_setprio(1);
#pragma unroll
    for (int m = 0; m < 4; ++m)
#pragma unroll
      for (int n = 0; n < 2; ++n)
#pragma unroll
        for (int k = 0; k < 2; ++k)
          acc[m + 4][n] = __builtin_amdgcn_mfma_f32_16x16x32_bf16(aF[m][k], bA[n][k], acc[m + 4][n], 0, 0, 0);
    __builtin_amdgcn_s_setprio(0);
    __builtin_amdgcn_s_barrier();

    // ---- P3: stage Bh1,Ah0,Ah1(t+2); mfma q(m4-7, n2-3); vmcnt(8) ----
    if (t + 2 < NT) { stageB(t + 2, 1); stageA(t + 2, 0); stageA(t + 2, 1); }
    __builtin_amdgcn_s_setprio(1);
#pragma unroll
    for (int m = 0; m < 4; ++m)
#pragma unroll
      for (int n = 0; n < 2; ++n)
#pragma unroll
        for (int k = 0; k < 2; ++k)
          acc[m + 4][n + 2] = __builtin_amdgcn_mfma_f32_16x16x32_bf16(aF[m][k], bB[n][k], acc[m + 4][n + 2], 0, 0, 0);
    __builtin_amdgcn_s_setprio(0);
    if (t + 2 < NT) { asm volatile("s_waitcnt vmcnt(8)" ::: "memory"); }
    else            { asm volatile("s_waitcnt vmcnt(0)" ::: "memory"); }
    __builtin_amdgcn_s_barrier();
  }

  // ---- epilogue: in-LDS transpose, 2 m-halves, coalesced stores ----
  const int lrb = wr * 64 + (lane >> 4) * 4;  // + mi*16 + r  (0..127)
  const int lcol = wc * 64 + (lane & 15);     // + n*16
#pragma unroll
  for (int mh = 0; mh < 2; ++mh) {
    if (mh) __builtin_amdgcn_s_barrier();
    if constexpr (QEPI) {
      float* lf = (float*)lds;  // 128 x 256 fp32
#pragma unroll
      for (int mi = 0; mi < 4; ++mi)
#pragma unroll
        for (int n = 0; n < 4; ++n)
#pragma unroll
          for (int r = 0; r < 4; ++r)
            lf[(lrb + mi * 16 + r) * 256 + lcol + n * 16] = acc[mh * 4 + mi][n][r];
      __builtin_amdgcn_s_barrier();
#pragma unroll
      for (int j = 0; j < 16; ++j) {
        int cidx = j * 512 + tid;    // 0..8191 float4 chunks
        int lr = cidx >> 6;
        int cc = cidx & 63;
        int grow = R0 + (lr >> 6) * 128 + mh * 64 + (lr & 63);
        float4 v = *(float4*)(lf + lr * 256 + cc * 4);
        float4 bq4 = *(const float4*)(bq + C0 + cc * 4);
        float4 wv = *(const float4*)(weighted + (size_t)(grow & (T_ - 1)) * H_ + C0 + cc * 4);
        float4 o;
        o.x = wv.x / (1.f + __expf(-(v.x + bq4.x)));
        o.y = wv.y / (1.f + __expf(-(v.y + bq4.y)));
        o.z = wv.z / (1.f + __expf(-(v.z + bq4.z)));
        o.w = wv.w / (1.f + __expf(-(v.w + bq4.w)));
        *(float4*)(out + (size_t)grow * NCOLS + C0 + cc * 4) = o;
      }
    } else {
      ushort* lh = lds;  // 128 x 256 bf16
#pragma unroll
      for (int mi = 0; mi < 4; ++mi)
#pragma unroll
        for (int n = 0; n < 4; ++n)
#pragma unroll
          for (int r = 0; r < 4; ++r)
            lh[(lrb + mi * 16 + r) * 256 + lcol + n * 16] = f2b(acc[mh * 4 + mi][n][r]);
      __builtin_amdgcn_s_barrier();
#pragma unroll
      for (int j = 0; j < 8; ++j) {
        int cidx = j * 512 + tid;    // 0..4095 chunks of 8 bf16
        int lr = cidx >> 5;
        int cc = cidx & 31;
        int grow = R0 + (lr >> 6) * 128 + mh * 64 + (lr & 63);
        uint4 v = *(uint4*)(lh + lr * 256 + cc * 8);
        *(uint4*)(KVout + (size_t)grow * NCOLS + C0 + cc * 8) = v;
      }
    }
  }
}

// Batch reduction: weighted[t,h] = sum_b exp(K+bk+wb)*(V+bv) / sum_b exp(K+bk+wb)
__global__ __launch_bounds__(256) void reduce_kernel(
    const ushort* __restrict__ KV, const float* __restrict__ bk,
    const float* __restrict__ bv, const float* __restrict__ wb,
    float* __restrict__ weighted) {
  const int gid = blockIdx.x * 256 + threadIdx.x;
  const int t = gid >> 7;
  const int h0 = (gid & 127) * 8;

  float bk8[8], bv8[8], wb8[8];
#pragma unroll
  for (int j = 0; j < 8; ++j) {
    bk8[j] = bk[h0 + j];
    bv8[j] = bv[h0 + j];
    wb8[j] = wb[h0 + j];
  }

  float sn[8] = {}, sw[8] = {};
  for (int b = 0; b < B_; ++b) {
    const size_t rowoff = (size_t)(b * T_ + t) * (2 * H_);
    const short8 k8 = *(const short8*)(KV + rowoff + h0);
    const short8 v8 = *(const short8*)(KV + rowoff + H_ + h0);
#pragma unroll
    for (int j = 0; j < 8; ++j) {
      float e = __expf(b2f((ushort)k8[j]) + bk8[j] + wb8[j]);
      sn[j] += e;
      sw[j] += e * (b2f((ushort)v8[j]) + bv8[j]);
    }
  }
  float4 o0, o1;
  o0.x = sw[0] / sn[0]; o0.y = sw[1] / sn[1]; o0.z = sw[2] / sn[2]; o0.w = sw[3] / sn[3];
  o1.x = sw[4] / sn[4]; o1.y = sw[5] / sn[5]; o1.z = sw[6] / sn[6]; o1.w = sw[7] / sn[7];
  *(float4*)(weighted + (size_t)t * H_ + h0) = o0;
  *(float4*)(weighted + (size_t)t * H_ + h0 + 4) = o1;
}

extern "C" void kernel_launch(void* const* d_in, const int* in_sizes, int n_in,
                              void* d_out, int out_size, void* d_ws, size_t ws_size,
                              hipStream_t stream) {
  (void)in_sizes; (void)n_in; (void)out_size; (void)ws_size;
  const float* x = (const float*)d_in[0];
  const float* Wq = (const float*)d_in[1];
  const float* bq = (const float*)d_in[2];
  const float* Wk = (const float*)d_in[3];
  const float* bk = (const float*)d_in[4];
  const float* Wv = (const float*)d_in[5];
  const float* bv = (const float*)d_in[6];
  const float* wbias = (const float*)d_in[7];
  float* out = (float*)d_out;

  char* ws = (char*)d_ws;
  const size_t XN = (size_t)B_ * T_ * D_;   // 33,554,432
  const size_t WN = (size_t)H_ * D_;        // 1,048,576
  ushort* xb   = (ushort*)ws;                            // 64 MiB
  ushort* Wqb  = (ushort*)(ws + XN * 2);                 // 2 MiB
  ushort* Wkvb = Wqb + WN;                               // 4 MiB (Wk|Wv contiguous)
  float* weighted = (float*)(ws + XN * 2 + 3 * WN * 2);  // 16 MiB
  ushort* KV = (ushort*)(ws + XN * 2 + 3 * WN * 2 + (size_t)T_ * H_ * 4);  // 128 MiB

  (void)hipFuncSetAttribute((const void*)gemm_bt<2048, false>,
                            hipFuncAttributeMaxDynamicSharedMemorySize, 131072);
  (void)hipFuncSetAttribute((const void*)gemm_bt<1024, true>,
                            hipFuncAttributeMaxDynamicSharedMemorySize, 131072);

  cvt_kernel<<<2048, 256, 0, stream>>>(x, xb, (int)XN);
  cvt3_kernel<<<dim3(512, 3), 256, 0, stream>>>(Wq, Wk, Wv, Wqb, (int)WN);

  gemm_bt<2048, false><<<dim3((B_ * T_) / 256, 2048 / 256), 512, 131072, stream>>>(
      xb, Wkvb, KV, nullptr, nullptr, nullptr);
  reduce_kernel<<<(T_ * H_ / 8) / 256, 256, 0, stream>>>(KV, bk, bv, wbias, weighted);
  gemm_bt<1024, true><<<dim3((B_ * T_) / 256, 1024 / 256), 512, 131072, stream>>>(
      xb, Wqb, nullptr, bq, weighted, out);
}